// Round 4
// baseline (322.297 us; speedup 1.0000x reference)
//
#include <hip/hip_runtime.h>
#include <stdint.h>

// ---------------------------------------------------------------------------
// JAX Threefry-2x32 (20 rounds), key = jax.random.key(42) -> (k0,k1) = (0,42)
// ---------------------------------------------------------------------------
__device__ __forceinline__ unsigned int rotl32(unsigned int x, unsigned int d) {
    return (x << d) | (x >> (32u - d));
}

__device__ __forceinline__ void threefry2x32_key0_42(unsigned int c0, unsigned int c1,
                                                     unsigned int& o0, unsigned int& o1) {
    const unsigned int ks0 = 0u;
    const unsigned int ks1 = 42u;
    const unsigned int ks2 = 0x1BD11BDAu ^ 0u ^ 42u;
    unsigned int x0 = c0 + ks0;
    unsigned int x1 = c1 + ks1;
#define TF_RND(r) { x0 += x1; x1 = rotl32(x1, (r)); x1 ^= x0; }
    TF_RND(13) TF_RND(15) TF_RND(26) TF_RND(6)
    x0 += ks1; x1 += ks2 + 1u;
    TF_RND(17) TF_RND(29) TF_RND(16) TF_RND(24)
    x0 += ks2; x1 += ks0 + 2u;
    TF_RND(13) TF_RND(15) TF_RND(26) TF_RND(6)
    x0 += ks0; x1 += ks1 + 3u;
    TF_RND(17) TF_RND(29) TF_RND(16) TF_RND(24)
    x0 += ks1; x1 += ks2 + 4u;
    TF_RND(13) TF_RND(15) TF_RND(26) TF_RND(6)
    x0 += ks2; x1 += ks0 + 5u;
#undef TF_RND
    o0 = x0; o1 = x1;
}

// jax_threefry_partitionable=True, bit_width=32: bits[n] = o0 ^ o1, counter (0, n)
__device__ __forceinline__ float jax_uniform_u01(unsigned int n) {
    unsigned int o0, o1;
    threefry2x32_key0_42(0u, n, o0, o1);
    unsigned int bits = o0 ^ o1;
    unsigned int fb = (bits >> 9) | 0x3F800000u;
    float u = __uint_as_float(fb) - 1.0f;
    return fmaxf(u, 0.0f);
}

// ---------------------------------------------------------------------------
// Kernel 1: eps[j] = (1+tanh(t))*exp(-t/tau_s)/tau_s, plus per-1024-element
// "any nonzero" BYTE flags (one block per chunk). Tail bytes up to the next
// 8-byte boundary are zeroed so kernel 2 can test 8 chunks per uint64 load
// (d_ws is poisoned 0xAA — unwritten tail bytes would read as nonzero).
// ---------------------------------------------------------------------------
__global__ __launch_bounds__(1024) void eps_flags_kernel(
    const float* __restrict__ tss,
    const float* __restrict__ tau_s,
    float* __restrict__ eps,
    unsigned char* __restrict__ flags, int N) {
    const int i = blockIdx.x * 1024 + threadIdx.x;
    float e = 0.0f;
    if (i < N) {
        float t  = tss[i] - 1.0f;   // DELTA_DELAY = 1.0
        float ts = tau_s[i];
        e = (1.0f + tanhf(t)) * expf(-t / ts) / ts;
        eps[i] = e;
    }
    unsigned long long m = __ballot(e != 0.0f);
    __shared__ int wany[16];
    const int wid = threadIdx.x >> 6;
    if ((threadIdx.x & 63) == 0) wany[wid] = (m != 0ull) ? 1 : 0;
    __syncthreads();
    if (threadIdx.x == 0) {
        int any = 0;
        #pragma unroll
        for (int k = 0; k < 16; ++k) any |= wany[k];
        flags[blockIdx.x] = (unsigned char)any;
    }
    // zero pad bytes so the last uint64 word reads clean
    if (blockIdx.x == 0 && threadIdx.x < 8) {
        const int nchunks = (N + 1023) >> 10;
        const int nwords8 = ((nchunks + 7) >> 3) << 3;
        int p = nchunks + (int)threadIdx.x;
        if (p < nwords8) flags[p] = 0;
    }
}

// ---------------------------------------------------------------------------
// Kernel 2: one wave per row (4 rows / 256-thread block). Single uint64 load
// gives 8 chunk flags at once; mask==0 (the SNN common case: no recent
// spikes -> eps underflows to exactly 0) skips the chunk loop, the shuffle
// reduction, and the eps/diagonal loads. Threefry + per-row scalar loads are
// issued BEFORE the mask check so their latency overlaps it.
// ---------------------------------------------------------------------------
__global__ __launch_bounds__(256) void row_update_kernel(
    const float* __restrict__ w,
    const float* __restrict__ eps,
    const unsigned char* __restrict__ flags,
    const float* __restrict__ I_ext,
    const float* __restrict__ v,
    const float* __restrict__ spiked,
    const float* __restrict__ tss,
    const float* __restrict__ theta_v,
    const float* __restrict__ tau_m,
    const float* __restrict__ tau_theta,
    const float* __restrict__ J_theta,
    const float* __restrict__ E_L,
    const float* __restrict__ c,
    const float* __restrict__ Delta_u,
    const float* __restrict__ theta_inf,
    float* __restrict__ out, int N) {

    const int wid  = threadIdx.x >> 6;        // wave id within block: 0..3
    const int lane = threadIdx.x & 63;
    const int row  = blockIdx.x * 4 + wid;
    if (row >= N) return;

    // ---- issue independent latency-bound work up front ----
    // per-row scalar loads (wave-uniform address -> broadcast, 1 txn each)
    const float r_theta_v   = theta_v[row];
    const float r_theta_inf = theta_inf[row];
    const float r_J_theta   = J_theta[row];
    const float r_spiked    = spiked[row];
    const float r_tau_theta = tau_theta[row];
    const float r_v         = v[row];
    const float r_E_L       = E_L[row];
    const float r_I_ext     = I_ext[row];
    const float r_tau_m     = tau_m[row];
    const float r_tss       = tss[row];
    const float r_c         = c[row];
    const float r_Delta_u   = Delta_u[row];
    // threefry on all lanes: pure VALU, overlaps the loads above
    const float u = jax_uniform_u01((unsigned int)row);

    const int nchunks = (N + 1023) >> 10;     // 1024-element chunks
    const int nwords  = (nchunks + 7) >> 3;   // uint64 flag words
    const unsigned long long* __restrict__ f8 = (const unsigned long long*)flags;

    unsigned long long mask_all = 0ull;
    for (int wd = 0; wd < nwords; ++wd) mask_all |= f8[wd];

    float acc = 0.0f;
    float er  = 0.0f;
    if (mask_all != 0ull) {                   // rare (dense-eps) path
        const float4* __restrict__ wrow = (const float4*)(w + (size_t)row * (size_t)N);
        const float4* __restrict__ e4   = (const float4*)eps;
        const int n4 = N >> 2;
        float a0 = 0.0f, a1 = 0.0f, a2 = 0.0f, a3 = 0.0f;
        for (int ch = 0; ch < nchunks; ++ch) {
            if (flags[ch] == 0) continue;     // wave-uniform skip
            const int base = (ch << 8) + lane;
            if (base < n4) {
                float4 wv = wrow[base]; float4 ev = e4[base];
                a0 = fmaf(wv.x, ev.x, fmaf(wv.y, ev.y, fmaf(wv.z, ev.z, fmaf(wv.w, ev.w, a0))));
            }
            if (base + 64 < n4) {
                float4 wv = wrow[base + 64]; float4 ev = e4[base + 64];
                a1 = fmaf(wv.x, ev.x, fmaf(wv.y, ev.y, fmaf(wv.z, ev.z, fmaf(wv.w, ev.w, a1))));
            }
            if (base + 128 < n4) {
                float4 wv = wrow[base + 128]; float4 ev = e4[base + 128];
                a2 = fmaf(wv.x, ev.x, fmaf(wv.y, ev.y, fmaf(wv.z, ev.z, fmaf(wv.w, ev.w, a2))));
            }
            if (base + 192 < n4) {
                float4 wv = wrow[base + 192]; float4 ev = e4[base + 192];
                a3 = fmaf(wv.x, ev.x, fmaf(wv.y, ev.y, fmaf(wv.z, ev.z, fmaf(wv.w, ev.w, a3))));
            }
        }
        acc = (a0 + a1) + (a2 + a3);
        #pragma unroll
        for (int off = 32; off > 0; off >>= 1)
            acc += __shfl_down(acc, off, 64);
        er = eps[row];
    }

    if (lane == 0) {
        float I_syn = acc;
        if (er != 0.0f) I_syn -= w[(size_t)row * (size_t)N + row] * er;  // zero diagonal

        float th = r_theta_v + (r_theta_inf - r_theta_v + r_J_theta * r_spiked) / r_tau_theta;
        float v_next = r_v + (r_E_L - r_v + r_I_ext) / r_tau_m + I_syn;

        float notref = (r_tss > 2.0f) ? 1.0f : 0.0f;      // T_REFRACTORY = 2.0
        float lam = notref * r_c * expf((v_next - th) / r_Delta_u);
        lam = fminf(fmaxf(lam, 0.0f), 1.0f);

        float s = (u < lam) ? 1.0f : 0.0f;
        float v_new = (1.0f - s) * v_next;                // RESET_POTENTIAL = 0

        out[row]         = lam;     // spikes_lambda
        out[N + row]     = s;       // spiked_new
        out[2 * N + row] = v_new;   // v_new
    }
}

extern "C" void kernel_launch(void* const* d_in, const int* in_sizes, int n_in,
                              void* d_out, int out_size, void* d_ws, size_t ws_size,
                              hipStream_t stream) {
    const int N = in_sizes[0];
    const float* I_ext     = (const float*)d_in[0];
    const float* w         = (const float*)d_in[1];
    const float* v         = (const float*)d_in[2];
    const float* spiked    = (const float*)d_in[3];
    const float* tss       = (const float*)d_in[4];
    const float* theta_v   = (const float*)d_in[5];
    const float* tau_m     = (const float*)d_in[6];
    const float* tau_s     = (const float*)d_in[7];
    const float* tau_theta = (const float*)d_in[8];
    const float* J_theta   = (const float*)d_in[9];
    const float* E_L       = (const float*)d_in[10];
    const float* c         = (const float*)d_in[11];
    const float* Delta_u   = (const float*)d_in[12];
    const float* theta_inf = (const float*)d_in[13];
    float* out = (float*)d_out;
    float*         eps   = (float*)d_ws;                                   // N floats
    unsigned char* flags = (unsigned char*)d_ws + (size_t)N * sizeof(float); // 8B-aligned

    const int nchunks = (N + 1023) / 1024;
    hipLaunchKernelGGL(eps_flags_kernel, dim3(nchunks), dim3(1024), 0, stream,
                       tss, tau_s, eps, flags, N);
    hipLaunchKernelGGL(row_update_kernel, dim3((N + 3) / 4), dim3(256), 0, stream,
                       w, eps, flags, I_ext, v, spiked, tss, theta_v, tau_m, tau_theta,
                       J_theta, E_L, c, Delta_u, theta_inf, out, N);
}